// Round 10
// baseline (316.567 us; speedup 1.0000x reference)
//
#include <hip/hip_runtime.h>
#include <hip/hip_bf16.h>

// ---------------------------------------------------------------------------
// NeRF-style aggregator, MI355X (gfx950). R5 (resubmit x5 — bench never ran).
// Changes vs R4 (VALU cuts; R4 showed VALUBusy 54% dominant):
//  - All LDS read/store addresses hoisted out of K-loop AND layer loop
//    (XOR-swizzle decomposed into 2 bases + 128B immediate steps).
//  - Bias pre-loaded into MFMA accumulator (C-in) -> no epilogue adds.
//  - Density dot spread over 512 threads + shfl_xor reduce (was 1 wave).
// ---------------------------------------------------------------------------

using f32x4 = __attribute__((ext_vector_type(4))) float;
using s16x8 = __attribute__((ext_vector_type(8))) short;

__device__ __forceinline__ unsigned short f2bf(float f) {
  union { float f; unsigned int u; } a; a.f = f;
  unsigned int r = (a.u + 0x7fffu + ((a.u >> 16) & 1u)) >> 16;   // RTNE
  return (unsigned short)r;
}
__device__ __forceinline__ float bf2f(unsigned short h) {
  union { unsigned int u; float f; } a; a.u = ((unsigned int)h) << 16; return a.f;
}
__device__ __forceinline__ unsigned int pack2(float a, float b) {
  __hip_bfloat162 h2 = __float22bfloat162_rn(make_float2(a, b));
  union { __hip_bfloat162 h; unsigned int u; } cv; cv.h = h2; return cv.u;
}
__device__ __forceinline__ void mfma16(f32x4& c, const s16x8& a, const s16x8& b) {
  // v_mfma_f32_16x16x32_bf16. A: row=lane&15, k=(lane>>4)*8+j. B: col=lane&15,
  // k=(lane>>4)*8+j. D: col=lane&15, row=(lane>>4)*4+reg.
  asm("v_mfma_f32_16x16x32_bf16 %0, %1, %2, %0" : "+v"(c) : "v"(a), "v"(b));
}
__device__ __forceinline__ float lrelu(float v) { return fmaxf(v, 0.01f * v); }
__device__ __forceinline__ float softplus1(float x) {
  return fmaxf(x, 0.f) + log1pf(expf(-fabsf(x)));
}

// Packed weight offsets (bf16 elements) inside workspace (unchanged):
//   W1_in:   [0, 65536)               ksteps=8,  nfb=16
//   W1_h[i]: [65536*(1+i), ...)       ksteps=8,  nfb=16   (i=0..3)
//   Wc_in:   [327680, 368640)         ksteps=10, nfb=8    (K padded 280->320)
//   Wc_h[i]: [368640+i*16384, ...)    ksteps=4,  nfb=8
#define PACK_TOTAL 401408
#define RAD_BYTE_OFF (1 << 20)

__global__ void pack_kernel(const float* __restrict__ W1_in, const float* __restrict__ W1_h,
                            const float* __restrict__ Wc_in, const float* __restrict__ Wc_h,
                            unsigned short* __restrict__ wpack) {
  int p = blockIdx.x * 256 + threadIdx.x;
  if (p >= PACK_TOTAL) return;
  const float* src; int q, ncb, krows, ldn;
  if (p < 327680) {
    int mi = p >> 16; q = p & 65535;
    if (mi == 0) { src = W1_in; krows = 254; } else { src = W1_h + (mi - 1) * 65536; krows = 256; }
    ncb = 16; ldn = 256;
  } else if (p < 368640) {
    q = p - 327680; src = Wc_in; krows = 280; ncb = 8; ldn = 128;
  } else {
    int t = p - 368640; int mi = t >> 14; q = t & 16383;
    src = Wc_h + mi * 16384; krows = 128; ncb = 8; ldn = 128;
  }
  int frag = q >> 9, within = q & 511;
  int lane = within >> 3, j = within & 7;
  int cb = frag % ncb, ks = frag / ncb;
  int k = ks * 32 + ((lane >> 4) << 3) + j;
  int col = cb * 16 + (lane & 15);
  float v = (k < krows) ? src[k * ldn + col] : 0.f;
  wpack[p] = f2bf(v);
}

// One MLP layer, IN-PLACE, all addresses precomputed by the caller.
// rbo[sf*2+p] = LDS byte offset of the (ks&1)==p read base for sample-frag sf;
// per-ks step is (ks>>1)*128 (compile-time immediate). sto[ff*SF+sf] = store
// offset. Bias is loaded into the accumulator (MFMA C-in) -> free bias add.
// wpL must be pre-offset by (fbase*64 + lane).
template <int KSTEPS, int FF, int SF, int NFB>
__device__ __forceinline__ void layer_T(
    char* __restrict__ buf, const unsigned* rbo, const unsigned* sto,
    const s16x8* __restrict__ wpL, const float* __restrict__ bias,
    int fbase, int l4) {
  f32x4 acc[FF][SF];
#pragma unroll
  for (int ff = 0; ff < FF; ++ff) {
    const float4 b4 = *(const float4*)(bias + (fbase + ff) * 16 + l4 * 4);
#pragma unroll
    for (int sf = 0; sf < SF; ++sf) acc[ff][sf] = (f32x4){b4.x, b4.y, b4.z, b4.w};
  }
#pragma unroll
  for (int ks = 0; ks < KSTEPS; ++ks) {
    s16x8 w[FF], x[SF];
#pragma unroll
    for (int ff = 0; ff < FF; ++ff) w[ff] = wpL[(ks * NFB + ff) * 64];
    const int qo = (ks >> 1) * 128;
#pragma unroll
    for (int sf = 0; sf < SF; ++sf)
      x[sf] = *(const s16x8*)(buf + rbo[sf * 2 + (ks & 1)] + qo);
#pragma unroll
    for (int ff = 0; ff < FF; ++ff)
#pragma unroll
      for (int sf = 0; sf < SF; ++sf) mfma16(acc[ff][sf], w[ff], x[sf]);
  }
  __syncthreads();   // all reads done before any in-place write
#pragma unroll
  for (int ff = 0; ff < FF; ++ff)
#pragma unroll
    for (int sf = 0; sf < SF; ++sf) {
      float v0 = lrelu(acc[ff][sf][0]);
      float v1 = lrelu(acc[ff][sf][1]);
      float v2 = lrelu(acc[ff][sf][2]);
      float v3 = lrelu(acc[ff][sf][3]);
      uint2 p; p.x = pack2(v0, v1); p.y = pack2(v2, v3);
      *(uint2*)(buf + sto[ff * SF + sf]) = p;
    }
}

// Phase A: per-sample MLP (5 layers, 256-wide) + density + masked aggregation.
// 512 thr = 8 f-waves (FF=2, SF=4 covering all 64 rows). LDS 33312 B.
__global__ __launch_bounds__(512, 6) void phaseA_kernel(
    const float* __restrict__ rel_loc, const float* __restrict__ feat,
    const int* __restrict__ mask, const unsigned short* __restrict__ wpack,
    const float* __restrict__ b1_in, const float* __restrict__ b1_h,
    const float* __restrict__ Ws, const float* __restrict__ bs,
    float* __restrict__ out, unsigned short* __restrict__ rad) {
  extern __shared__ char smem[];
  char* buf = smem;                              // 64 x 512 B
  float* wv   = (float*)(smem + 32768);          // 64 normalized agg weights
  float* wsum = (float*)(smem + 32768 + 256);    // 8
  float* dpt  = (float*)(smem + 32768 + 288);    // 64
  const int tid = threadIdx.x;
  const int lane = tid & 63, wid = tid >> 6;
  const int l15 = lane & 15, l4 = lane >> 4;
  const int fbase = wid * 2;          // 8 f-waves x FF=2 -> 16 ffrags (256 cols)
  const int row0 = blockIdx.x * 64;

  // ---- build input features (bf16, XOR-swizzled) ----
  for (int idx = tid; idx < 64 * 32; idx += 512) {
    int r = idx >> 5, d = idx & 31;
    float v = feat[(row0 + r) * 32 + d];
    int sw = (r & 7) << 4;
    char* rowp = buf + r * 512;
    *(unsigned short*)(rowp + ((d * 2) ^ sw)) = f2bf(v);
    float s, c;
    __sincosf(v, &s, &c);
#pragma unroll
    for (int f = 0; f < 3; ++f) {                // cols 32 + (d*3+f)*2 + {0,1}
      *(unsigned int*)(rowp + ((64 + (d * 3 + f) * 4) ^ sw)) = pack2(s, c);
      float s2 = 2.f * s * c, c2 = 1.f - 2.f * s * s;
      s = s2; c = c2;
    }
  }
  for (int idx = tid; idx < 64 * 3; idx += 512) {
    int r = idx / 3, c = idx - r * 3;
    float v = rel_loc[(row0 + r) * 3 + c];
    int sw = (r & 7) << 4;
    char* rowp = buf + r * 512;
    float s, cc;
    __sincosf(v, &s, &cc);
#pragma unroll
    for (int f = 0; f < 5; ++f) {                // cols 224 + (c*5+f)*2 + {0,1}
      *(unsigned int*)(rowp + ((448 + (c * 5 + f) * 4) ^ sw)) = pack2(s, cc);
      float s2 = 2.f * s * cc, c2 = 1.f - 2.f * s * s;
      s = s2; cc = c2;
    }
  }
  if (tid < 64) {                  // zero-pad cols 254,255 + raw agg weights
    int r = tid;
    *(unsigned int*)(buf + r * 512 + (508 ^ ((r & 7) << 4))) = 0;
    float x = rel_loc[(row0 + r) * 3 + 0];
    float y = rel_loc[(row0 + r) * 3 + 1];
    float z = rel_loc[(row0 + r) * 3 + 2];
    float dist = sqrtf(x * x + y * y + z * z);
    float m = (mask[row0 + r] != 0) ? 1.f : 0.f;
    wv[r] = m / fmaxf(dist, 1e-8f);
  }
  __syncthreads();
  if (tid < 8) {
    float ssum = 0.f;
#pragma unroll
    for (int k = 0; k < 8; ++k) ssum += wv[tid * 8 + k];
    wsum[tid] = fmaxf(ssum, 1e-8f);
  }
  __syncthreads();
  if (tid < 64) wv[tid] = wv[tid] / wsum[tid >> 3];

  // ---- hoisted LDS addressing (layer-invariant) ----
  unsigned rbo[8], sto[8];
#pragma unroll
  for (int sf = 0; sf < 4; ++sf) {
    int row = sf * 16 + l15;
    unsigned rowb = row * 512;
    int sw = (row & 7) << 4;
    rbo[sf * 2 + 0] = rowb + ((l4 * 16) ^ sw);
    rbo[sf * 2 + 1] = rowb + ((64 + l4 * 16) ^ sw);
#pragma unroll
    for (int ff = 0; ff < 2; ++ff)
      sto[ff * 4 + sf] = rowb + ((((fbase + ff) * 32) + l4 * 8) ^ sw);
  }

  // ---- 5 MLP layers, in place ----
#pragma unroll 1
  for (int L = 0; L < 5; ++L) {
    __syncthreads();
    const s16x8* wpL = (const s16x8*)(wpack + L * 65536) + (fbase * 64 + lane);
    const float* bias = (L == 0) ? b1_in : (b1_h + (L - 1) * 256);
    layer_T<8, 2, 4, 16>(buf, rbo, sto, wpL, bias, fbase, l4);
  }
  __syncthreads();

  // ---- density per sample, spread over all 512 threads ----
  {
    int r = tid >> 3, sub = tid & 7;     // 64 rows x 8 sub-slices
    const char* rowp = buf + r * 512;
    int rsw = (r & 7) << 4;
    float s = 0.f;
#pragma unroll
    for (int i = 0; i < 4; ++i) {
      int c16 = sub * 4 + i;
      s16x8 v = *(const s16x8*)(rowp + ((c16 * 16) ^ rsw));
      const float* wsrc = Ws + c16 * 8;
#pragma unroll
      for (int j = 0; j < 8; ++j) s += bf2f((unsigned short)v[j]) * wsrc[j];
    }
    s += __shfl_xor(s, 1);
    s += __shfl_xor(s, 2);
    s += __shfl_xor(s, 4);
    if (sub == 0) dpt[r] = softplus1(s + bs[0] - 1.f);
  }
  __syncthreads();

  // ---- masked weighted aggregation over k=8 (one uint2 col-group/thread) ----
  {
    int nn = tid >> 6, c4 = tid & 63;    // 8 points x 64 col-groups = 512
    float a0 = 0.f, a1 = 0.f, a2 = 0.f, a3 = 0.f;
#pragma unroll
    for (int k = 0; k < 8; ++k) {
      int r = nn * 8 + k;
      uint2 u = *(const uint2*)(buf + r * 512 + ((c4 * 8) ^ ((r & 7) << 4)));
      float w = wv[r];
      a0 += w * bf2f((unsigned short)(u.x & 0xffffu));
      a1 += w * bf2f((unsigned short)(u.x >> 16));
      a2 += w * bf2f((unsigned short)(u.y & 0xffffu));
      a3 += w * bf2f((unsigned short)(u.y >> 16));
    }
    uint2 p; p.x = pack2(a0, a1); p.y = pack2(a2, a3);
    *(uint2*)(rad + (row0 / 8 + nn) * 256 + c4 * 4) = p;
  }
  if (tid < 8) {
    float s = 0.f;
#pragma unroll
    for (int k = 0; k < 8; ++k) s += wv[tid * 8 + k] * dpt[tid * 8 + k];
    out[(row0 / 8 + tid) * 4] = s;   // density
  }
}

// Phase B: color MLP (280->128->128->128->3), 64 points/block -> 512 blocks.
// 8 waves = 4 f-waves (FF=2) x 2 s-waves (SF=2). LDS 64x640 = 40960 B.
__global__ __launch_bounds__(512, 4) void phaseB_kernel(
    const unsigned short* __restrict__ rad, const float* __restrict__ viewdir,
    const unsigned short* __restrict__ wpack, const float* __restrict__ bc_in,
    const float* __restrict__ bc_h, const float* __restrict__ Wc_out,
    const float* __restrict__ bc_out, float* __restrict__ out) {
  extern __shared__ char smem[];
  char* buf = smem;   // 64 x 640 B
  const int tid = threadIdx.x;
  const int lane = tid & 63, wid = tid >> 6;
  const int l15 = lane & 15, l4 = lane >> 4;
  const int fbase = (wid >> 1) * 2;   // 4 f-waves x FF=2 -> 8 ffrags (128 cols)
  const int sbase = (wid & 1) * 2;    // 2 s-waves x SF=2 -> 4 sfrags (64 rows)
  const int g0 = blockIdx.x * 64;

  for (int idx = tid; idx < 64 * 32; idx += 512) {    // radiance cols 0..255
    int r = idx >> 5, c8 = idx & 31;
    s16x8 v = *(const s16x8*)(rad + (g0 + r) * 256 + c8 * 8);
    *(s16x8*)(buf + r * 640 + ((c8 * 16) ^ ((r & 7) << 4))) = v;
  }
  for (int idx = tid; idx < 64 * 3; idx += 512) {     // posenc(viewdir): cols 256..279
    int r = idx / 3, c = idx - r * 3;
    float v = viewdir[(g0 + r) * 3 + c];
    int sw = (r & 7) << 4;
    char* rowp = buf + r * 640;
    float s, cc;
    __sincosf(v, &s, &cc);
#pragma unroll
    for (int f = 0; f < 4; ++f) {
      *(unsigned int*)(rowp + ((512 + (c * 4 + f) * 4) ^ sw)) = pack2(s, cc);
      float s2 = 2.f * s * cc, c2 = 1.f - 2.f * s * s;
      s = s2; cc = c2;
    }
  }
  for (int idx = tid; idx < 64 * 20; idx += 512) {    // zero cols 280..319
    int r = idx / 20, i = idx - r * 20;
    *(unsigned int*)(buf + r * 640 + ((560 + i * 4) ^ ((r & 7) << 4))) = 0;
  }

  // hoisted LDS addressing (layer-invariant)
  unsigned rbo[4], sto[4];
#pragma unroll
  for (int sf = 0; sf < 2; ++sf) {
    int row = (sbase + sf) * 16 + l15;
    unsigned rowb = row * 640;
    int sw = (row & 7) << 4;
    rbo[sf * 2 + 0] = rowb + ((l4 * 16) ^ sw);
    rbo[sf * 2 + 1] = rowb + ((64 + l4 * 16) ^ sw);
#pragma unroll
    for (int ff = 0; ff < 2; ++ff)
      sto[ff * 2 + sf] = rowb + ((((fbase + ff) * 32) + l4 * 8) ^ sw);
  }
  __syncthreads();
  layer_T<10, 2, 2, 8>(buf, rbo, sto, (const s16x8*)(wpack + 327680) + (fbase * 64 + lane), bc_in, fbase, l4);
  __syncthreads();
  layer_T<4, 2, 2, 8>(buf, rbo, sto, (const s16x8*)(wpack + 368640) + (fbase * 64 + lane), bc_h, fbase, l4);
  __syncthreads();
  layer_T<4, 2, 2, 8>(buf, rbo, sto, (const s16x8*)(wpack + 385024) + (fbase * 64 + lane), bc_h + 128, fbase, l4);
  __syncthreads();

  if (tid < 64) {   // final 128 -> 3 + sigmoid epilogue
    int r = tid, rsw = (r & 7) << 4;
    const char* rowp = buf + r * 640;
    float d0 = 0.f, d1 = 0.f, d2 = 0.f;
    for (int c16 = 0; c16 < 16; ++c16) {
      s16x8 v = *(const s16x8*)(rowp + ((c16 * 16) ^ rsw));
#pragma unroll
      for (int j = 0; j < 8; ++j) {
        float hv = bf2f((unsigned short)v[j]);
        const float* wr = Wc_out + (c16 * 8 + j) * 3;
        d0 += hv * wr[0]; d1 += hv * wr[1]; d2 += hv * wr[2];
      }
    }
    float o0 = d0 + bc_out[0], o1 = d1 + bc_out[1], o2 = d2 + bc_out[2];
    out[(g0 + r) * 4 + 1] = 1.002f / (1.f + __expf(-o0)) - 0.001f;
    out[(g0 + r) * 4 + 2] = 1.002f / (1.f + __expf(-o1)) - 0.001f;
    out[(g0 + r) * 4 + 3] = 1.002f / (1.f + __expf(-o2)) - 0.001f;
  }
}

extern "C" void kernel_launch(void* const* d_in, const int* in_sizes, int n_in,
                              void* d_out, int out_size, void* d_ws, size_t ws_size,
                              hipStream_t stream) {
  const float* rel_loc = (const float*)d_in[0];
  const float* feat    = (const float*)d_in[1];
  const int*   mask    = (const int*)d_in[2];
  const float* viewdir = (const float*)d_in[3];
  const float* W1_in   = (const float*)d_in[4];
  const float* b1_in   = (const float*)d_in[5];
  const float* W1_h    = (const float*)d_in[6];
  const float* b1_h    = (const float*)d_in[7];
  const float* Ws      = (const float*)d_in[8];
  const float* bs      = (const float*)d_in[9];
  const float* Wc_in   = (const float*)d_in[10];
  const float* bc_in   = (const float*)d_in[11];
  const float* Wc_h    = (const float*)d_in[12];
  const float* bc_h    = (const float*)d_in[13];
  const float* Wc_out  = (const float*)d_in[14];
  const float* bc_out  = (const float*)d_in[15];
  float* out = (float*)d_out;
  unsigned short* wpack = (unsigned short*)d_ws;
  unsigned short* rad = (unsigned short*)((char*)d_ws + RAD_BYTE_OFF);

  const int n = in_sizes[3] / 3;          // 32768 points
  const int blocksA = n * 8 / 64;         // 4096
  const int blocksB = n / 64;             // 512

  hipFuncSetAttribute((const void*)phaseA_kernel, hipFuncAttributeMaxDynamicSharedMemorySize, 33312);
  hipFuncSetAttribute((const void*)phaseB_kernel, hipFuncAttributeMaxDynamicSharedMemorySize, 40960);

  pack_kernel<<<(PACK_TOTAL + 255) / 256, 256, 0, stream>>>(W1_in, W1_h, Wc_in, Wc_h, wpack);
  phaseA_kernel<<<blocksA, 512, 33312, stream>>>(rel_loc, feat, mask, wpack, b1_in, b1_h, Ws, bs, out, rad);
  phaseB_kernel<<<blocksB, 512, 40960, stream>>>(rad, viewdir, wpack, bc_in, bc_h, Wc_out, bc_out, out);
}